// Round 4
// baseline (987.469 us; speedup 1.0000x reference)
//
#include <hip/hip_runtime.h>
#include <hip/hip_bf16.h>
#include <stdint.h>

typedef __attribute__((ext_vector_type(8))) __bf16 bf16x8;
typedef __attribute__((ext_vector_type(4))) float f32x4;

static constexpr int kTokens = 8192;   // B*S = 4*2048
static constexpr int kHid    = 2048;   // H
static constexpr int kInter  = 8192;   // I
static constexpr int kN1     = 16384;  // 2*I, branch-interleaved in 16-col groups

// ---------------- async global->LDS 16B copy (global_load_lds_dwordx4) ----
__device__ __forceinline__ void async16(const void* g, void* l) {
  using gp = const __attribute__((address_space(1))) unsigned int*;
  using lp = __attribute__((address_space(3))) unsigned int*;
  __builtin_amdgcn_global_load_lds((gp)(uintptr_t)g,
                                   (lp)(unsigned int)(uintptr_t)l, 16, 0, 0);
}

// ---------------- LayerNorm (f32 in) -> bf16 y --------------------------
__global__ __launch_bounds__(256) void ln_kernel(
    const float* __restrict__ x, const float* __restrict__ gamma,
    const float* __restrict__ beta, __hip_bfloat16* __restrict__ y) {
  const int t = threadIdx.x;
  const size_t row = blockIdx.x;
  const float* xr = x + row * kHid;
  float4 v0 = ((const float4*)xr)[2 * t];
  float4 v1 = ((const float4*)xr)[2 * t + 1];
  float s  = v0.x + v0.y + v0.z + v0.w + v1.x + v1.y + v1.z + v1.w;
  float s2 = v0.x*v0.x + v0.y*v0.y + v0.z*v0.z + v0.w*v0.w
           + v1.x*v1.x + v1.y*v1.y + v1.z*v1.z + v1.w*v1.w;
#pragma unroll
  for (int off = 1; off < 64; off <<= 1) {
    s  += __shfl_xor(s, off, 64);
    s2 += __shfl_xor(s2, off, 64);
  }
  __shared__ float red[8];
  const int w = t >> 6;
  if ((t & 63) == 0) { red[w] = s; red[4 + w] = s2; }
  __syncthreads();
  s  = red[0] + red[1] + red[2] + red[3];
  s2 = red[4] + red[5] + red[6] + red[7];
  const float mu = s * (1.0f / kHid);
  const float rs = rsqrtf(s2 * (1.0f / kHid) - mu * mu + 1e-6f);
  float4 g0 = ((const float4*)gamma)[2 * t], g1 = ((const float4*)gamma)[2 * t + 1];
  float4 b0 = ((const float4*)beta)[2 * t],  b1 = ((const float4*)beta)[2 * t + 1];
  union { __hip_bfloat16 h[8]; uint4 u; } pk;
  pk.h[0] = __float2bfloat16((v0.x - mu) * rs * g0.x + b0.x);
  pk.h[1] = __float2bfloat16((v0.y - mu) * rs * g0.y + b0.y);
  pk.h[2] = __float2bfloat16((v0.z - mu) * rs * g0.z + b0.z);
  pk.h[3] = __float2bfloat16((v0.w - mu) * rs * g0.w + b0.w);
  pk.h[4] = __float2bfloat16((v1.x - mu) * rs * g1.x + b1.x);
  pk.h[5] = __float2bfloat16((v1.y - mu) * rs * g1.y + b1.y);
  pk.h[6] = __float2bfloat16((v1.z - mu) * rs * g1.z + b1.z);
  pk.h[7] = __float2bfloat16((v1.w - mu) * rs * g1.w + b1.w);
  ((uint4*)(y + row * kHid))[t] = pk.u;
}

// ---------------- f32 (K x Ncols) -> bf16 transposed (N x K) -------------
template <bool INTERLEAVE>
__global__ __launch_bounds__(256) void cvt_tr(
    const float* __restrict__ src, __hip_bfloat16* __restrict__ dst,
    int K, int N) {
  __shared__ float tile[64][65];
  const int nb = blockIdx.x * 64;
  const int kb = blockIdx.y * 64;
  const int t = threadIdx.x;
#pragma unroll
  for (int it = 0; it < 16; ++it) {
    int p = t + it * 256;
    int lk = p >> 6, ln = p & 63;
    int n = nb + ln;
    int col = INTERLEAVE ? ((((n >> 4) & 1) << 13) + (((n >> 5) << 4) | (n & 15)))
                         : n;
    tile[lk][ln] = src[(size_t)(kb + lk) * N + col];
  }
  __syncthreads();
#pragma unroll
  for (int it = 0; it < 16; ++it) {
    int p = t + it * 256;
    int ln = p >> 6, lk = p & 63;
    dst[(size_t)(nb + ln) * K + kb + lk] = __float2bfloat16(tile[lk][ln]);
  }
}

// ---------------- 256x256 8-phase bf16 GEMM  C = A(MxK) * B^T(NxK) -------
// m201-template port: BK=64, 8 waves (2Mx4N), 512 thr, 2x64KB LDS dbuf in
// 4 half-tile slots each + 8KB dummy sink. Counted vmcnt(4) at phases 4/8.
// XOR chunk swizzle (chunk ^= row&7): linear LDS dest, inverse-swizzled
// global source, swizzled ds_read.
//
// R3 delta: ds_reads moved INSIDE the MFMA region so the LDS drain runs
// UNDER the MFMAs (previously reads sat pre-barrier -> LDS and MFMA
// strictly alternated; per-K-tile 2487cyc MFMA + 1540cyc LDS serialized
// = measured 4970cyc, MfmaUtil 46%).
//   - af reads interleave at ii-granularity with the consuming phase's
//     MFMAs (compiler emits fine-grained counted lgkmcnt per use).
//   - bf01 prefetched 1 phase ahead in ph4/ph8 regions (slot dead there,
//     buf resident after that phase's vmcnt(4)); bf23 read in-region at
//     its consuming phase. Read ledger: 8/4/8/4/8/4/8/4 per phase.
//   - PHASE_MID's blanket lgkmcnt(0) removed (would re-serialize).
// Hazards re-verified: every slot rewrite follows its last MFMA use
// (wave-local program order); every LDS read follows staging residency
// (vmcnt chain); every LDS restage is >=1 barrier-pair after the last
// read of that slot. Zero new registers.
// Staging ledger (iter i): ph1:(2i+1).A0  ph2:(2i+1).A1  ph3:(2i+2).B0
// ph4:(2i+2).B1+VM  ph5:(2i+2).A0  ph6:(2i+2).A1  ph7:(2i+3).B0
// ph8:(2i+3).B1+VM.  Tail tiles stage dummies so vmcnt counts never change.
#define SLOT_A(b, h) ((b) * 65536 + (h) * 16384)
#define SLOT_B(b, h) ((b) * 65536 + 32768 + (h) * 16384)
#define SLOT_DUMMY 131072

template <int EPI, int NXTLOG>
__global__ __launch_bounds__(512, 2) void gemm8p(
    const __hip_bfloat16* __restrict__ A, const __hip_bfloat16* __restrict__ B,
    void* __restrict__ Cout, int M, int N, int K) {
  __shared__ __align__(16) char smem[139264];
  char* const sm = (char*)smem;

  const int t = threadIdx.x;
  const int lane = t & 63;
  const int wave = t >> 6;
  const int wm = wave >> 2;  // 0..1 (M waves)
  const int wn = wave & 3;   // 0..3 (N waves)

  // XCD-aware bijective swizzle (caller guarantees grid % 8 == 0)
  const int nwg = (int)gridDim.x;
  const int wg = ((int)blockIdx.x & 7) * (nwg >> 3) + ((int)blockIdx.x >> 3);
  const int bx = wg & ((1 << NXTLOG) - 1);
  const int by = wg >> NXTLOG;
  const size_t m0 = (size_t)by * 256;
  const size_t n0 = (size_t)bx * 256;

  // staging lane constants: thread t writes linear LDS bytes t*16 (+8192);
  // row = t>>3 (+64 for 2nd load), stored chunk = t&7, source chunk XOR'd.
  const int srow = t >> 3;
  const int scsrc = (t & 7) ^ (srow & 7);
  const __hip_bfloat16* const gA = A + (m0 + srow) * K + scsrc * 8;
  const __hip_bfloat16* const gB = B + (n0 + srow) * K + scsrc * 8;
  const size_t K64  = (size_t)64 * K;
  const size_t K128 = (size_t)128 * K;
  const int t16 = t * 16;
  char* const dm = sm + SLOT_DUMMY + t16;

  // fragment-read lane constants (row&7 == col&7 for all frag rows)
  const int col = lane & 15, q = lane >> 4;
  const int cs0 = (q ^ (col & 7)) * 16;        // kk=0 stored chunk
  const int cs1 = ((4 + q) ^ (col & 7)) * 16;  // kk=1
  const int aO0 = wm * 16384 + col * 128 + cs0;
  const int aO1 = wm * 16384 + col * 128 + cs1;
  const int bO0 = 32768 + (wn >> 1) * 16384 + ((wn & 1) * 64 + col) * 128 + cs0;
  const int bO1 = 32768 + (wn >> 1) * 16384 + ((wn & 1) * 64 + col) * 128 + cs1;

  f32x4 acc[8][4] = {};
  bf16x8 af[4][2], bf[4][2];

  const int NT = K >> 6;  // 64-wide K tiles (even for both GEMMs)
  const int L  = NT >> 1; // 2 tiles per iteration

#define STG_A(tile, h, buf)                                           \
  do {                                                                \
    const __hip_bfloat16* _s = gA + (size_t)(tile) * 64 + (h) * K128; \
    char* _d = sm + SLOT_A(buf, h) + t16;                             \
    async16(_s, _d);                                                  \
    async16(_s + K64, _d + 8192);                                     \
  } while (0)
#define STG_B(tile, h, buf)                                           \
  do {                                                                \
    const __hip_bfloat16* _s = gB + (size_t)(tile) * 64 + (h) * K128; \
    char* _d = sm + SLOT_B(buf, h) + t16;                             \
    async16(_s, _d);                                                  \
    async16(_s + K64, _d + 8192);                                     \
  } while (0)
#define STG_A_G(tile, h, buf)                  \
  do {                                         \
    if ((tile) < NT) { STG_A(tile, h, buf); }  \
    else { async16(A, dm); async16(A, dm); }   \
  } while (0)
#define STG_B_G(tile, h, buf)                  \
  do {                                         \
    if ((tile) < NT) { STG_B(tile, h, buf); }  \
    else { async16(A, dm); async16(A, dm); }   \
  } while (0)

  // single-ii af load (2 x ds_read_b128)
#define LOAD_A1(buf, mh, ii)                                                      \
  af[ii][0] = *(const bf16x8*)(sm + (buf)*65536 + aO0 + (mh)*8192 + (ii)*2048);   \
  af[ii][1] = *(const bf16x8*)(sm + (buf)*65536 + aO1 + (mh)*8192 + (ii)*2048);

#define LOAD_B(buf, nh)                                                        \
  { _Pragma("unroll") for (int jj = 0; jj < 2; ++jj) {                         \
      bf[(nh)*2 + jj][0] = *(const bf16x8*)(sm + (buf)*65536 + bO0 + ((nh)*2 + jj)*2048); \
      bf[(nh)*2 + jj][1] = *(const bf16x8*)(sm + (buf)*65536 + bO1 + ((nh)*2 + jj)*2048); \
  } }

  // 4 MFMAs consuming af[ii] (both kk) against bf pair nh
#define MFMA_II(mh, nh, ii)                                                    \
  { _Pragma("unroll") for (int kk = 0; kk < 2; ++kk)                           \
    _Pragma("unroll") for (int jj = 0; jj < 2; ++jj)                           \
      acc[(mh)*4 + (ii)][(nh)*2 + jj] = __builtin_amdgcn_mfma_f32_16x16x32_bf16( \
          af[ii][kk], bf[(nh)*2 + jj][kk], acc[(mh)*4 + (ii)][(nh)*2 + jj], 0, 0, 0); }

#define QUAD16(mh, nh) \
  MFMA_II(mh, nh, 0) MFMA_II(mh, nh, 1) MFMA_II(mh, nh, 2) MFMA_II(mh, nh, 3)

  // A-phase region: af reads interleaved at ii granularity with MFMAs
#define PHASE_A_BODY(buf, mh, nh)   \
  LOAD_A1(buf, mh, 0)               \
  LOAD_A1(buf, mh, 1)               \
  MFMA_II(mh, nh, 0)                \
  LOAD_A1(buf, mh, 2)               \
  MFMA_II(mh, nh, 1)                \
  LOAD_A1(buf, mh, 3)               \
  MFMA_II(mh, nh, 2)                \
  MFMA_II(mh, nh, 3)

#define PHASE_MID()                                  \
  __builtin_amdgcn_s_barrier();                      \
  __builtin_amdgcn_s_setprio(1)
#define PHASE_MID_VM()                               \
  asm volatile("s_waitcnt vmcnt(4)" ::: "memory");   \
  __builtin_amdgcn_s_barrier();                      \
  __builtin_amdgcn_s_setprio(1)
#define PHASE_END()                                  \
  __builtin_amdgcn_s_setprio(0);                     \
  __builtin_amdgcn_s_barrier()

  // prologue: tile0 {A,B} + tile1 {B}; vmcnt(4) leaves tile1.B in flight.
  // Then prefetch bf01(buf0) (loop-carried: ph8-region feeds ph1).
  STG_A(0, 0, 0);
  STG_A(0, 1, 0);
  STG_B(0, 0, 0);
  STG_B(0, 1, 0);
  STG_B(1, 0, 1);
  STG_B(1, 1, 1);
  asm volatile("s_waitcnt vmcnt(4)" ::: "memory");
  __builtin_amdgcn_s_barrier();
  LOAD_B(0, 0)

#pragma unroll 1
  for (int i = 0; i < L; ++i) {
    const int t1 = 2 * i + 1, t2 = 2 * i + 2, t3 = 2 * i + 3;
    // ph1: tile 2i (buf0) quad(0,0); in-region afm0 reads
    STG_A(t1, 0, 1);
    PHASE_MID();
    PHASE_A_BODY(0, 0, 0)
    PHASE_END();
    // ph2: quad(0,1); in-region bf23(buf0) reads
    STG_A(t1, 1, 1);
    PHASE_MID();
    LOAD_B(0, 1)
    QUAD16(0, 1)
    PHASE_END();
    // ph3: quad(1,0); in-region afm1(buf0) reads
    STG_B_G(t2, 0, 0);
    PHASE_MID();
    PHASE_A_BODY(0, 1, 0)
    PHASE_END();
    // ph4: quad(1,1); vmcnt(4) -> tile 2i+1 resident; prefetch bf01(buf1)
    STG_B_G(t2, 1, 0);
    PHASE_MID_VM();
    LOAD_B(1, 0)
    QUAD16(1, 1)
    PHASE_END();
    // ph5: tile 2i+1 (buf1) quad(0,0); in-region afm0 reads
    STG_A_G(t2, 0, 0);
    PHASE_MID();
    PHASE_A_BODY(1, 0, 0)
    PHASE_END();
    // ph6: quad(0,1); in-region bf23(buf1) reads
    STG_A_G(t2, 1, 0);
    PHASE_MID();
    LOAD_B(1, 1)
    QUAD16(0, 1)
    PHASE_END();
    // ph7: quad(1,0); in-region afm1(buf1) reads
    STG_B_G(t3, 0, 1);
    PHASE_MID();
    PHASE_A_BODY(1, 1, 0)
    PHASE_END();
    // ph8: quad(1,1); vmcnt(4) -> tile 2i+2 resident; prefetch bf01(buf0')
    // for next iteration's ph1 (stale-but-safe read on final iteration)
    STG_B_G(t3, 1, 1);
    PHASE_MID_VM();
    LOAD_B(0, 0)
    QUAD16(1, 1)
    PHASE_END();
  }
  asm volatile("s_waitcnt vmcnt(0)" ::: "memory");  // drain before LDS dealloc

  // C/D layout: col = lane&15, row = (lane>>4)*4 + reg   [m89-verified]
  const int gr0 = (int)m0 + wm * 128 + q * 4;
  if (EPI == 0) {
    float* Cf = (float*)Cout;
    const int gc0 = (int)n0 + wn * 64 + col;
#pragma unroll
    for (int mi = 0; mi < 8; ++mi)
#pragma unroll
      for (int j = 0; j < 4; ++j) {
        size_t base = (size_t)(gr0 + mi * 16) * N + gc0 + j * 16;
#pragma unroll
        for (int r = 0; r < 4; ++r) Cf[base + (size_t)r * N] = acc[mi][j][r];
      }
  } else {
    __hip_bfloat16* Z = (__hip_bfloat16*)Cout;
    const int ldz = N >> 1;
    const size_t ib0 = (n0 >> 1) + wn * 32 + col;
#pragma unroll
    for (int mi = 0; mi < 8; ++mi)
#pragma unroll
      for (int tp = 0; tp < 2; ++tp) {
        const f32x4 gg = acc[mi][2 * tp];      // gate (a=0) 16-col tile
        const f32x4 ll = acc[mi][2 * tp + 1];  // linear (a=1) 16-col tile
        size_t base = (size_t)(gr0 + mi * 16) * ldz + ib0 + tp * 16;
#pragma unroll
        for (int r = 0; r < 4; ++r) {
          // gelu_tanh(x) = x * sigmoid(2u), u = 0.79788456*(x + 0.044715 x^3)
          float xv = gg[r];
          float u = 0.7978845608028654f * xv * (1.0f + 0.044715f * xv * xv);
          float sg = __builtin_amdgcn_rcpf(1.0f + __expf(-2.0f * u));
          Z[base + (size_t)r * ldz] = __float2bfloat16(xv * sg * ll[r]);
        }
      }
  }
}

extern "C" void kernel_launch(void* const* d_in, const int* in_sizes, int n_in,
                              void* d_out, int out_size, void* d_ws, size_t ws_size,
                              hipStream_t stream) {
  const float* x     = (const float*)d_in[0];
  const float* gamma = (const float*)d_in[1];
  const float* beta  = (const float*)d_in[2];
  const float* W1    = (const float*)d_in[3];  // [H, 2, I] f32
  const float* W2    = (const float*)d_in[4];  // [I, H] f32
  float* out = (float*)d_out;

  char* ws = (char*)d_ws;
  __hip_bfloat16* yb  = (__hip_bfloat16*)ws;                    // 32 MB
  __hip_bfloat16* w1t = (__hip_bfloat16*)(ws + (32ull << 20));  // 64 MB
  __hip_bfloat16* w2t = (__hip_bfloat16*)(ws + (96ull << 20));  // 32 MB
  __hip_bfloat16* z   = (__hip_bfloat16*)(ws + (128ull << 20)); // 128 MB
  (void)in_sizes; (void)n_in; (void)out_size; (void)ws_size;

  ln_kernel<<<kTokens, 256, 0, stream>>>(x, gamma, beta, yb);
  cvt_tr<true ><<<dim3(kN1 / 64, kHid / 64), 256, 0, stream>>>(W1, w1t, kHid, kN1);
  cvt_tr<false><<<dim3(kHid / 64, kInter / 64), 256, 0, stream>>>(W2, w2t, kInter, kHid);
  // GEMM1: M=8192, N=16384, K=2048 -> grid 64*32 = 2048 (NXT=64 -> log 6)
  gemm8p<1, 6><<<dim3((kN1 / 256) * (kTokens / 256)), 512, 0, stream>>>(
      yb, w1t, (void*)z, kTokens, kN1, kHid);
  // GEMM2: M=8192, N=2048, K=8192 -> grid 8*32 = 256 (NXT=8 -> log 3)
  gemm8p<0, 3><<<dim3((kHid / 256) * (kTokens / 256)), 512, 0, stream>>>(
      z, w2t, (void*)out, kTokens, kHid, kInter);
}